// Round 3
// baseline (605.859 us; speedup 1.0000x reference)
//
#include <hip/hip_runtime.h>

// Problem sizes (fixed by reference)
#define B_N   8192
#define S_N   512
#define F_N   64
#define R_N   4096
#define D_N   256
#define T_N   16
#define SF_N  (S_N * F_N)

// Fused kernel tiling
#define BM    32                 // rows per block (grid = B_N/BM = 256 = 1 block/CU)
#define CT_W  512                // cols per col-tile
#define NCT   (R_N / CT_W)       // 8 col tiles
#define KC    16                 // k-chunk
#define NKC   (D_N / KC)         // 16 k chunks per col-tile
#define NCI   (NCT * NKC)        // 128 linear chunks

__device__ __forceinline__ void gld_lds16(const float* g, float* l) {
  __builtin_amdgcn_global_load_lds(
      (const __attribute__((address_space(1))) void*)g,
      (__attribute__((address_space(3))) void*)l, 16, 0, 0);
}

// ---------------- K0a: rsqh[r] = 0.5 * sum_k register[r][k]^2 ----------------
__global__ __launch_bounds__(256) void k_rsq(const float* __restrict__ reg,
                                             float* __restrict__ rsqh) {
  const int t = threadIdx.x;
  const int lane = t & 63;
  const int r = blockIdx.x * 4 + (t >> 6);
  const float4 v = *(const float4*)&reg[(size_t)r * D_N + lane * 4];
  float s = v.x * v.x + v.y * v.y + v.z * v.z + v.w * v.w;
#pragma unroll
  for (int m = 32; m >= 1; m >>= 1) s += __shfl_xor(s, m);
  if (lane == 0) rsqh[r] = 0.5f * s;
}

// ---------------- K0b: regT[k][r] = register[r][k] ----------------
__global__ __launch_bounds__(256) void k_transpose(const float* __restrict__ reg,
                                                   float* __restrict__ regT) {
  __shared__ float tile[64][65];
  const int t = threadIdx.x;
  const int r0 = blockIdx.x * 64;
  const int k0 = blockIdx.y * 64;
  const int a = t >> 2;  // 0..63
  const int q = t & 3;   // 0..3
#pragma unroll
  for (int i = 0; i < 4; ++i) {
    const int c = q * 16 + i * 4;
    const float4 v = *(const float4*)&reg[(size_t)(r0 + a) * D_N + k0 + c];
    tile[a][c + 0] = v.x; tile[a][c + 1] = v.y;
    tile[a][c + 2] = v.z; tile[a][c + 3] = v.w;
  }
  __syncthreads();
#pragma unroll
  for (int i = 0; i < 4; ++i) {
    const int rr = q * 16 + i * 4;
    float4 o;
    o.x = tile[rr + 0][a]; o.y = tile[rr + 1][a];
    o.z = tile[rr + 2][a]; o.w = tile[rr + 3][a];
    *(float4*)&regT[(size_t)(k0 + a) * R_N + r0 + rr] = o;
  }
}

// ---------------- Fused: mean+proj (phase 1) then score+argmin+emit (phase 2) --------
// LDS: Bb[2][16][512] floats = 64 KB; xm[32][64] (8 KB) aliased into Bb[0] (phase-disjoint).
__global__ __launch_bounds__(256, 1) void k_fused(const float* __restrict__ x,
                                                  const float* __restrict__ W,
                                                  const float* __restrict__ bias,
                                                  const float* __restrict__ reg,
                                                  const float* __restrict__ regT,
                                                  const float* __restrict__ rsqh,
                                                  float* __restrict__ xe_g,
                                                  float* __restrict__ out,
                                                  float* __restrict__ lossArr) {
  __shared__ __align__(16) float smem[2 * KC * CT_W];  // 64 KB
  float* xm = smem;                                    // [32][64], phase-1 only

  const int t = threadIdx.x;
  const int w = t >> 6;
  const int lane = t & 63;
  const int bm0 = blockIdx.x * BM;

  // ---------- Phase 1a: temporal mean for rows w*8..w*8+7 ----------
  {
    const int sg = lane >> 4;          // 0..3  (s subgroup)
    const int f4 = (lane & 15) * 4;    // feature base
#pragma unroll
    for (int rr = 0; rr < 8; ++rr) {
      const int row = w * 8 + rr;
      const float* xb = x + (size_t)(bm0 + row) * SF_N + f4;
      float4 a0 = make_float4(0.f, 0.f, 0.f, 0.f);
      float4 a1 = make_float4(0.f, 0.f, 0.f, 0.f);
      // s = sg + 4*i, i = 0..127 ; 1 KB contiguous per wave-instr
      for (int i = 0; i < 128; i += 4) {
        const float4 v0 = *(const float4*)&xb[(sg + 4 * (i + 0)) * F_N];
        const float4 v1 = *(const float4*)&xb[(sg + 4 * (i + 1)) * F_N];
        const float4 v2 = *(const float4*)&xb[(sg + 4 * (i + 2)) * F_N];
        const float4 v3 = *(const float4*)&xb[(sg + 4 * (i + 3)) * F_N];
        a0.x += v0.x + v2.x; a0.y += v0.y + v2.y; a0.z += v0.z + v2.z; a0.w += v0.w + v2.w;
        a1.x += v1.x + v3.x; a1.y += v1.y + v3.y; a1.z += v1.z + v3.z; a1.w += v1.w + v3.w;
      }
      float sx = a0.x + a1.x, sy = a0.y + a1.y, sz = a0.z + a1.z, sw = a0.w + a1.w;
#pragma unroll
      for (int m = 16; m <= 32; m <<= 1) {  // reduce across the 4 s-subgroups
        sx += __shfl_xor(sx, m); sy += __shfl_xor(sy, m);
        sz += __shfl_xor(sz, m); sw += __shfl_xor(sw, m);
      }
      if (sg == 0) {
        const float inv = 1.0f / (float)S_N;
        float4 o; o.x = sx * inv; o.y = sy * inv; o.z = sz * inv; o.w = sw * inv;
        *(float4*)&xm[row * F_N + f4] = o;
      }
    }
  }
  __syncthreads();

  // ---------- Phase 1b: projection, thread t = output dim d ----------
  {
    const int d = t;
    float4 wr[16];
#pragma unroll
    for (int k4 = 0; k4 < 16; ++k4)
      wr[k4] = *(const float4*)&W[(size_t)d * F_N + k4 * 4];
    const float bz = bias[d];
    for (int r = 0; r < BM; ++r) {
      float acc = bz;
#pragma unroll
      for (int k4 = 0; k4 < 16; ++k4) {
        const float4 xv = *(const float4*)&xm[r * F_N + k4 * 4];  // pure broadcast
        acc = fmaf(wr[k4].x, xv.x, acc);
        acc = fmaf(wr[k4].y, xv.y, acc);
        acc = fmaf(wr[k4].z, xv.z, acc);
        acc = fmaf(wr[k4].w, xv.w, acc);
      }
      xe_g[(size_t)(bm0 + r) * D_N + d] = acc;  // contiguous per instr
    }
  }
  __syncthreads();  // drains vmcnt -> xe visible in L2; xm dead, Bb usable

  // ---------- Phase 2: score all 4096 codes for our 32 rows ----------
  const int cg = lane;                    // col group 0..63
  const int rowbase = __builtin_amdgcn_readfirstlane(bm0 + w * 8);
  const float* xer = xe_g + (size_t)rowbase * D_N;  // wave-uniform base

  float acc[8][8];
  float bv[8];
  int bi[8];
#pragma unroll
  for (int mm = 0; mm < 8; ++mm) { bv[mm] = 3.4e38f; bi[mm] = 0; }

  auto stage = [&](int ci, int nbuf) {
    const int ct = ci >> 4, kc = ci & 15;
    float* Bn = smem + nbuf * (KC * CT_W);
#pragma unroll
    for (int i = 0; i < 8; ++i) {
      const int q = w * 8 + i;           // 0..31
      const int row = q >> 1, half = q & 1;
      gld_lds16(&regT[(size_t)(kc * KC + row) * R_N + ct * CT_W + half * 256 + lane * 4],
                &Bn[row * CT_W + half * 256 + lane * 4]);
    }
  };

  stage(0, 0);
  __syncthreads();
  int buf = 0;
  for (int ci = 0; ci < NCI; ++ci) {
    const int ct = ci >> 4, kc = ci & 15;
    if ((kc) == 0) {
#pragma unroll
      for (int mm = 0; mm < 8; ++mm)
#pragma unroll
        for (int cc = 0; cc < 8; ++cc) acc[mm][cc] = 0.f;
    }
    if (ci + 1 < NCI) stage(ci + 1, buf ^ 1);

    const float* Bc = smem + buf * (KC * CT_W);
    const int k0 = kc * KC;
#pragma unroll
    for (int kk = 0; kk < 4; ++kk) {
      float b0[4][4], b1[4][4];
#pragma unroll
      for (int j = 0; j < 4; ++j) {
        const float4 v0 = *(const float4*)&Bc[(kk * 4 + j) * CT_W + cg * 4];
        const float4 v1 = *(const float4*)&Bc[(kk * 4 + j) * CT_W + cg * 4 + 256];
        b0[j][0] = v0.x; b0[j][1] = v0.y; b0[j][2] = v0.z; b0[j][3] = v0.w;
        b1[j][0] = v1.x; b1[j][1] = v1.y; b1[j][2] = v1.z; b1[j][3] = v1.w;
      }
#pragma unroll
      for (int mm = 0; mm < 8; ++mm) {
        const float4 a4 = *(const float4*)&xer[mm * D_N + k0 + kk * 4];  // uniform addr
        float av[4] = {a4.x, a4.y, a4.z, a4.w};
#pragma unroll
        for (int j = 0; j < 4; ++j)
#pragma unroll
          for (int cc = 0; cc < 4; ++cc) {
            acc[mm][cc]     = fmaf(av[j], b0[j][cc], acc[mm][cc]);
            acc[mm][4 + cc] = fmaf(av[j], b1[j][cc], acc[mm][4 + cc]);
          }
      }
    }

    if (kc == 15) {  // col-tile epilogue: score = 0.5||reg||^2 - dot, running argmin
      const float4 q0 = *(const float4*)&rsqh[ct * CT_W + cg * 4];
      const float4 q1 = *(const float4*)&rsqh[ct * CT_W + cg * 4 + 256];
      const float r0a[4] = {q0.x, q0.y, q0.z, q0.w};
      const float r1a[4] = {q1.x, q1.y, q1.z, q1.w};
      const int cbase = ct * CT_W + cg * 4;
#pragma unroll
      for (int mm = 0; mm < 8; ++mm) {
#pragma unroll
        for (int cc = 0; cc < 4; ++cc) {  // lower-c block first (tie -> lowest idx)
          const float s = r0a[cc] - acc[mm][cc];
          if (s < bv[mm]) { bv[mm] = s; bi[mm] = cbase + cc; }
        }
#pragma unroll
        for (int cc = 0; cc < 4; ++cc) {
          const float s = r1a[cc] - acc[mm][4 + cc];
          if (s < bv[mm]) { bv[mm] = s; bi[mm] = cbase + 256 + cc; }
        }
      }
    }
    __syncthreads();
    buf ^= 1;
  }

  // ---------- Phase 3: per-row wave argmin, gather, emit tokens + loss ----------
#pragma unroll
  for (int mm = 0; mm < 8; ++mm) {
    float v = bv[mm];
    int ix = bi[mm];
#pragma unroll
    for (int m = 1; m <= 32; m <<= 1) {
      const float ov = __shfl_xor(v, m);
      const int oi = __shfl_xor(ix, m);
      if (ov < v || (ov == v && oi < ix)) { v = ov; ix = oi; }
    }
    const int b = bm0 + w * 8 + mm;
    const float4 sel = *(const float4*)&reg[(size_t)ix * D_N + lane * 4];
#pragma unroll
    for (int i = 0; i < T_N; ++i)
      *(float4*)&out[((size_t)b * T_N + i) * D_N + lane * 4] = sel;
    const float4 xv = *(const float4*)&xe_g[(size_t)b * D_N + lane * 4];
    const float ex = xv.x - sel.x, ey = xv.y - sel.y, ez = xv.z - sel.z, ew = xv.w - sel.w;
    float p = ex * ex + ey * ey + ez * ez + ew * ew;
#pragma unroll
    for (int m = 32; m >= 1; m >>= 1) p += __shfl_xor(p, m);
    if (lane == 0) lossArr[b] = p;
  }
}

// ---------------- K4: loss = mean over B ----------------
__global__ __launch_bounds__(256) void k_loss(const float* __restrict__ lossArr,
                                              float* __restrict__ out) {
  __shared__ float ws4[4];
  const int t = threadIdx.x;
  float s = 0.f;
  for (int i = t; i < B_N; i += 256) s += lossArr[i];
#pragma unroll
  for (int m = 32; m >= 1; m >>= 1) s += __shfl_xor(s, m);
  if ((t & 63) == 0) ws4[t >> 6] = s;
  __syncthreads();
  if (t == 0)
    out[(size_t)B_N * T_N * D_N] = (ws4[0] + ws4[1] + ws4[2] + ws4[3]) / (float)B_N;
}

extern "C" void kernel_launch(void* const* d_in, const int* in_sizes, int n_in,
                              void* d_out, int out_size, void* d_ws, size_t ws_size,
                              hipStream_t stream) {
  const float* x    = (const float*)d_in[0];
  const float* W    = (const float*)d_in[1];
  const float* bias = (const float*)d_in[2];
  const float* reg  = (const float*)d_in[3];
  float* out = (float*)d_out;
  float* ws  = (float*)d_ws;

  // workspace layout (floats): all regions fully rewritten every call
  float* xe      = ws;                            // 8192*256
  float* regT    = xe + (size_t)B_N * D_N;        // 256*4096
  float* rsqh    = regT + (size_t)D_N * R_N;      // 4096
  float* lossArr = rsqh + R_N;                    // 8192

  k_rsq<<<dim3(R_N / 4), dim3(256), 0, stream>>>(reg, rsqh);
  k_transpose<<<dim3(R_N / 64, D_N / 64), dim3(256), 0, stream>>>(reg, regT);
  k_fused<<<dim3(B_N / BM), dim3(256), 0, stream>>>(x, W, bias, reg, regT, rsqh,
                                                    xe, out, lossArr);
  k_loss<<<dim3(1), dim3(256), 0, stream>>>(lossArr, out);
}

// Round 4
// 538.951 us; speedup vs baseline: 1.1241x; 1.1241x over previous
//
#include <hip/hip_runtime.h>

// Problem sizes (fixed by reference)
#define B_N   8192
#define S_N   512
#define F_N   64
#define R_N   4096
#define D_N   256
#define T_N   16

// K2 (score/argmin GEMM) tiling: block = 64 rows x 512 cols, KC=8
#define CS_BM 64
#define CS_CW 512
#define CS_KC 8
#define CS_NJ  (R_N / CS_CW)   // 8 col tiles
#define CS_NCH (D_N / CS_KC)   // 32 k chunks

__device__ __forceinline__ void gld_lds16(const float* g, float* l) {
  __builtin_amdgcn_global_load_lds(
      (const __attribute__((address_space(1))) void*)g,
      (__attribute__((address_space(3))) void*)l, 16, 0, 0);
}

// ---------------- K0a: rsqh[r] = 0.5 * sum_k register[r][k]^2 ----------------
__global__ __launch_bounds__(256) void k_rsq(const float* __restrict__ reg,
                                             float* __restrict__ rsqh) {
  const int t = threadIdx.x;
  const int lane = t & 63;
  const int r = blockIdx.x * 4 + (t >> 6);
  const float4 v = *(const float4*)&reg[(size_t)r * D_N + lane * 4];
  float s = v.x * v.x + v.y * v.y + v.z * v.z + v.w * v.w;
#pragma unroll
  for (int m = 32; m >= 1; m >>= 1) s += __shfl_xor(s, m);
  if (lane == 0) rsqh[r] = 0.5f * s;
}

// ---------------- K0b: regT[k][r] = register[r][k] ----------------
__global__ __launch_bounds__(256) void k_transpose(const float* __restrict__ reg,
                                                   float* __restrict__ regT) {
  __shared__ float tile[64][65];
  const int t = threadIdx.x;
  const int r0 = blockIdx.x * 64;
  const int k0 = blockIdx.y * 64;
  const int a = t >> 2;  // 0..63
  const int q = t & 3;   // 0..3
#pragma unroll
  for (int i = 0; i < 4; ++i) {
    const int c = q * 16 + i * 4;
    const float4 v = *(const float4*)&reg[(size_t)(r0 + a) * D_N + k0 + c];
    tile[a][c + 0] = v.x; tile[a][c + 1] = v.y;
    tile[a][c + 2] = v.z; tile[a][c + 3] = v.w;
  }
  __syncthreads();
#pragma unroll
  for (int i = 0; i < 4; ++i) {
    const int rr = q * 16 + i * 4;
    float4 o;
    o.x = tile[rr + 0][a]; o.y = tile[rr + 1][a];
    o.z = tile[rr + 2][a]; o.w = tile[rr + 3][a];
    *(float4*)&regT[(size_t)(k0 + a) * R_N + r0 + rr] = o;
  }
}

// ---------------- K1: temporal mean over S + projection to xe[b][d] ----------------
__global__ __launch_bounds__(256) void k_meanproj(const float* __restrict__ x,
                                                  const float* __restrict__ W,
                                                  const float* __restrict__ bias,
                                                  float* __restrict__ xe) {
  __shared__ __align__(16) float4 red[256];
  __shared__ __align__(16) float xm[F_N];
  const int b = blockIdx.x;
  const int t = threadIdx.x;
  const float* xb = x + (size_t)b * (S_N * F_N);
  const int sg = t >> 4;         // 0..15 (s subgroup)
  const int f4 = (t & 15) * 4;   // feature base
  float4 acc = make_float4(0.f, 0.f, 0.f, 0.f);
#pragma unroll 4
  for (int s = sg; s < S_N; s += 16) {
    const float4 v = *(const float4*)&xb[s * F_N + f4];
    acc.x += v.x; acc.y += v.y; acc.z += v.z; acc.w += v.w;
  }
  red[t] = acc;
  __syncthreads();
  if (t < 16) {
    float4 a = red[t];
#pragma unroll
    for (int g = 1; g < 16; ++g) {
      const float4 o = red[g * 16 + t];
      a.x += o.x; a.y += o.y; a.z += o.z; a.w += o.w;
    }
    const float inv = 1.0f / (float)S_N;
    xm[t * 4 + 0] = a.x * inv; xm[t * 4 + 1] = a.y * inv;
    xm[t * 4 + 2] = a.z * inv; xm[t * 4 + 3] = a.w * inv;
  }
  __syncthreads();
  // projection: thread t computes xe[b][t]
  float p = bias[t];
#pragma unroll
  for (int k4 = 0; k4 < F_N / 4; ++k4) {
    const float4 wv = *(const float4*)&W[(size_t)t * F_N + k4 * 4];
    const float4 xv = *(const float4*)&xm[k4 * 4];
    p = fmaf(wv.x, xv.x, p);
    p = fmaf(wv.y, xv.y, p);
    p = fmaf(wv.z, xv.z, p);
    p = fmaf(wv.w, xv.w, p);
  }
  xe[(size_t)b * D_N + t] = p;
}

// ---------------- K2: score = 0.5*||reg_r||^2 - xe.reg_r ; per-tile argmin ----------------
// 16x8 per-thread tile: 24 ds_read_b128 per 512 FMA-instr -> VALU-bound (LDS at ~75%)
__global__ __launch_bounds__(256, 2) void k_score(const float* __restrict__ xe,
                                                  const float* __restrict__ regT,
                                                  const float* __restrict__ rsqh,
                                                  float* __restrict__ pval,
                                                  int* __restrict__ pidx) {
  __shared__ __align__(16) float lA[2][CS_BM * CS_KC];  // 2 x 2 KB  (xe tile [m][k])
  __shared__ __align__(16) float lB[2][CS_KC * CS_CW];  // 2 x 16 KB (regT tile [k][c])
  const int t = threadIdx.x;
  const int w = t >> 6;     // wave 0..3 -> row group (16 rows each)
  const int lane = t & 63;
  const int jb = blockIdx.x;            // col tile 0..7
  const int bm0 = blockIdx.y * CS_BM;   // row base
  const int m0 = w * 16;
  const int c0 = lane * 4;              // col group base (plus +256 half)

  float acc[16][8];  // [row][col] ; cols 0-3 = c0 block, 4-7 = c0+256 block
#pragma unroll
  for (int mm = 0; mm < 16; ++mm)
#pragma unroll
    for (int cc = 0; cc < 8; ++cc) acc[mm][cc] = 0.f;

  auto stage = [&](int ch, int nb) {
    const int k0 = ch * CS_KC;
    // B: [8][512] = 16 KB = 16 lane-1KB loads; wave w takes q = w*4..w*4+3
#pragma unroll
    for (int i = 0; i < 4; ++i) {
      const int q = w * 4 + i;
      gld_lds16(&regT[(size_t)(k0 + (q >> 1)) * R_N + jb * CS_CW + (q & 1) * 256 + lane * 4],
                &lB[nb][(q >> 1) * CS_CW + (q & 1) * 256 + lane * 4]);
    }
    // A: [64][8] = 2 KB = 2 lane-1KB loads; waves 0,1 (wave-uniform branch)
    if (w < 2)
      gld_lds16(&xe[(size_t)(bm0 + w * 32 + (lane >> 1)) * D_N + k0 + (lane & 1) * 4],
                &lA[nb][w * 256 + lane * 4]);
  };

  stage(0, 0);
  __syncthreads();
  int buf = 0;
  for (int ch = 0; ch < CS_NCH; ++ch) {
    if (ch + 1 < CS_NCH) stage(ch + 1, buf ^ 1);
#pragma unroll
    for (int ks = 0; ks < 2; ++ks) {  // two 4-k steps per chunk
      float b0[4][4], b1[4][4];
#pragma unroll
      for (int j = 0; j < 4; ++j) {
        const float4 v0 = *(const float4*)&lB[buf][(ks * 4 + j) * CS_CW + c0];        // 16B stride
        const float4 v1 = *(const float4*)&lB[buf][(ks * 4 + j) * CS_CW + c0 + 256];  // 16B stride
        b0[j][0] = v0.x; b0[j][1] = v0.y; b0[j][2] = v0.z; b0[j][3] = v0.w;
        b1[j][0] = v1.x; b1[j][1] = v1.y; b1[j][2] = v1.z; b1[j][3] = v1.w;
      }
#pragma unroll
      for (int mm = 0; mm < 16; ++mm) {
        const float4 a4 = *(const float4*)&lA[buf][(m0 + mm) * CS_KC + ks * 4];  // broadcast
        const float av[4] = {a4.x, a4.y, a4.z, a4.w};
#pragma unroll
        for (int j = 0; j < 4; ++j)
#pragma unroll
          for (int cc = 0; cc < 4; ++cc) {
            acc[mm][cc]     = fmaf(av[j], b0[j][cc], acc[mm][cc]);
            acc[mm][4 + cc] = fmaf(av[j], b1[j][cc], acc[mm][4 + cc]);
          }
      }
    }
    __syncthreads();
    buf ^= 1;
  }

  // epilogue: score = 0.5*||reg||^2 - dot ; per-row argmin over this col tile
  const float4 q0 = *(const float4*)&rsqh[jb * CS_CW + c0];
  const float4 q1 = *(const float4*)&rsqh[jb * CS_CW + c0 + 256];
  const float r0a[4] = {q0.x, q0.y, q0.z, q0.w};
  const float r1a[4] = {q1.x, q1.y, q1.z, q1.w};
  const int cbase = jb * CS_CW + c0;
#pragma unroll
  for (int mm = 0; mm < 16; ++mm) {
    float bv = r0a[0] - acc[mm][0];
    int bi = cbase;
#pragma unroll
    for (int cc = 1; cc < 4; ++cc) {  // ascending index, strict < -> lowest idx wins
      const float s = r0a[cc] - acc[mm][cc];
      if (s < bv) { bv = s; bi = cbase + cc; }
    }
#pragma unroll
    for (int cc = 0; cc < 4; ++cc) {
      const float s = r1a[cc] - acc[mm][4 + cc];
      if (s < bv) { bv = s; bi = cbase + 256 + cc; }
    }
#pragma unroll
    for (int m = 32; m >= 1; m >>= 1) {
      const float ov = __shfl_xor(bv, m);
      const int oi = __shfl_xor(bi, m);
      if (ov < bv || (ov == bv && oi < bi)) { bv = ov; bi = oi; }
    }
    if (lane == 0) {
      pval[(size_t)(bm0 + m0 + mm) * CS_NJ + jb] = bv;
      pidx[(size_t)(bm0 + m0 + mm) * CS_NJ + jb] = bi;
    }
  }
}

// ---------------- K3: reduce partials, gather codebook row, write Xd + per-b loss ----------------
__global__ __launch_bounds__(256) void k_final(const float* __restrict__ reg,
                                               const float* __restrict__ xe,
                                               const float* __restrict__ pval,
                                               const int* __restrict__ pidx,
                                               float* __restrict__ out,
                                               float* __restrict__ lossArr) {
  const int b = blockIdx.x;
  const int t = threadIdx.x;
  const int lane = t & 63;
  const int w = t >> 6;
  // argmin over 8 tile partials (every 8-lane group does the same reduce)
  float bv = pval[(size_t)b * CS_NJ + (t & 7)];
  int bi = pidx[(size_t)b * CS_NJ + (t & 7)];
#pragma unroll
  for (int m = 4; m >= 1; m >>= 1) {
    const float ov = __shfl_xor(bv, m);
    const int oi = __shfl_xor(bi, m);
    if (ov < bv || (ov == bv && oi < bi)) { bv = ov; bi = oi; }
  }
  const int d4 = lane * 4;
  const float4 sel = *(const float4*)&reg[(size_t)bi * D_N + d4];
  // tile selected row across T_N tokens (1 KB contiguous per wave-instr)
#pragma unroll
  for (int tt0 = 0; tt0 < T_N / 4; ++tt0) {
    const int tt = tt0 * 4 + w;
    *(float4*)&out[(size_t)b * (T_N * D_N) + (size_t)tt * D_N + d4] = sel;
  }
  // per-b loss partial (each wave computes the full row sum; wave0 writes)
  const float4 xv = *(const float4*)&xe[(size_t)b * D_N + d4];
  const float ex = xv.x - sel.x, ey = xv.y - sel.y, ez = xv.z - sel.z, ew = xv.w - sel.w;
  float p = ex * ex + ey * ey + ez * ez + ew * ew;
#pragma unroll
  for (int m = 32; m >= 1; m >>= 1) p += __shfl_xor(p, m);
  if (t == 0) lossArr[b] = p;
}

// ---------------- K4: loss = mean over B ----------------
__global__ __launch_bounds__(256) void k_loss(const float* __restrict__ lossArr,
                                              float* __restrict__ out) {
  __shared__ float ws4[4];
  const int t = threadIdx.x;
  float s = 0.f;
  for (int i = t; i < B_N; i += 256) s += lossArr[i];
#pragma unroll
  for (int m = 32; m >= 1; m >>= 1) s += __shfl_xor(s, m);
  if ((t & 63) == 0) ws4[t >> 6] = s;
  __syncthreads();
  if (t == 0)
    out[(size_t)B_N * T_N * D_N] = (ws4[0] + ws4[1] + ws4[2] + ws4[3]) / (float)B_N;
}

extern "C" void kernel_launch(void* const* d_in, const int* in_sizes, int n_in,
                              void* d_out, int out_size, void* d_ws, size_t ws_size,
                              hipStream_t stream) {
  const float* x    = (const float*)d_in[0];
  const float* W    = (const float*)d_in[1];
  const float* bias = (const float*)d_in[2];
  const float* reg  = (const float*)d_in[3];
  float* out = (float*)d_out;
  float* ws  = (float*)d_ws;

  // workspace layout (floats): all regions fully rewritten every call
  float* xe      = ws;                            // 8192*256
  float* regT    = xe + (size_t)B_N * D_N;        // 256*4096
  float* rsqh    = regT + (size_t)D_N * R_N;      // 4096
  float* pval    = rsqh + R_N;                    // 8192*8
  int*   pidx    = (int*)(pval + (size_t)B_N * CS_NJ);  // 8192*8
  float* lossArr = (float*)pidx + (size_t)B_N * CS_NJ;  // 8192

  k_rsq<<<dim3(R_N / 4), dim3(256), 0, stream>>>(reg, rsqh);
  k_transpose<<<dim3(R_N / 64, D_N / 64), dim3(256), 0, stream>>>(reg, regT);
  k_meanproj<<<dim3(B_N), dim3(256), 0, stream>>>(x, W, bias, xe);
  k_score<<<dim3(CS_NJ, B_N / CS_BM), dim3(256), 0, stream>>>(xe, regT, rsqh, pval, pidx);
  k_final<<<dim3(B_N), dim3(256), 0, stream>>>(reg, xe, pval, pidx, out, lossArr);
  k_loss<<<dim3(1), dim3(256), 0, stream>>>(lossArr, out);
}

// Round 5
// 486.305 us; speedup vs baseline: 1.2458x; 1.1083x over previous
//
#include <hip/hip_runtime.h>

// Problem sizes (fixed by reference)
#define B_N   8192
#define S_N   512
#define F_N   64
#define R_N   4096
#define D_N   256
#define T_N   16

// K2 (score/argmin GEMM): block = 64 rows x 512 cols, 8 waves, 8x8 thread tile
#define CS_BM 64
#define CS_CW 512
#define CS_KC 8
#define CS_NJ  (R_N / CS_CW)   // 8 col tiles
#define CS_NCH (D_N / CS_KC)   // 32 k chunks

__device__ __forceinline__ void gld_lds16(const float* g, float* l) {
  __builtin_amdgcn_global_load_lds(
      (const __attribute__((address_space(1))) void*)g,
      (__attribute__((address_space(3))) void*)l, 16, 0, 0);
}

// ---------------- K0a: rsqh[r] = 0.5 * sum_k register[r][k]^2 ----------------
__global__ __launch_bounds__(256) void k_rsq(const float* __restrict__ reg,
                                             float* __restrict__ rsqh) {
  const int t = threadIdx.x;
  const int lane = t & 63;
  const int r = blockIdx.x * 4 + (t >> 6);
  const float4 v = *(const float4*)&reg[(size_t)r * D_N + lane * 4];
  float s = v.x * v.x + v.y * v.y + v.z * v.z + v.w * v.w;
#pragma unroll
  for (int m = 32; m >= 1; m >>= 1) s += __shfl_xor(s, m);
  if (lane == 0) rsqh[r] = 0.5f * s;
}

// ---------------- K0b: regT[k][r] = register[r][k] ----------------
__global__ __launch_bounds__(256) void k_transpose(const float* __restrict__ reg,
                                                   float* __restrict__ regT) {
  __shared__ float tile[64][65];
  const int t = threadIdx.x;
  const int r0 = blockIdx.x * 64;
  const int k0 = blockIdx.y * 64;
  const int a = t >> 2;  // 0..63
  const int q = t & 3;   // 0..3
#pragma unroll
  for (int i = 0; i < 4; ++i) {
    const int c = q * 16 + i * 4;
    const float4 v = *(const float4*)&reg[(size_t)(r0 + a) * D_N + k0 + c];
    tile[a][c + 0] = v.x; tile[a][c + 1] = v.y;
    tile[a][c + 2] = v.z; tile[a][c + 3] = v.w;
  }
  __syncthreads();
#pragma unroll
  for (int i = 0; i < 4; ++i) {
    const int rr = q * 16 + i * 4;
    float4 o;
    o.x = tile[rr + 0][a]; o.y = tile[rr + 1][a];
    o.z = tile[rr + 2][a]; o.w = tile[rr + 3][a];
    *(float4*)&regT[(size_t)(k0 + a) * R_N + r0 + rr] = o;
  }
}

// ---------------- K1: temporal mean over S + projection to xe[b][d] ----------------
__global__ __launch_bounds__(256) void k_meanproj(const float* __restrict__ x,
                                                  const float* __restrict__ W,
                                                  const float* __restrict__ bias,
                                                  float* __restrict__ xe) {
  __shared__ __align__(16) float4 red[256];
  __shared__ __align__(16) float xm[F_N];
  const int b = blockIdx.x;
  const int t = threadIdx.x;
  const float* xb = x + (size_t)b * (S_N * F_N);
  const int sg = t >> 4;         // 0..15 (s subgroup)
  const int f4 = (t & 15) * 4;   // feature base
  float4 acc = make_float4(0.f, 0.f, 0.f, 0.f);
#pragma unroll 4
  for (int s = sg; s < S_N; s += 16) {
    const float4 v = *(const float4*)&xb[s * F_N + f4];
    acc.x += v.x; acc.y += v.y; acc.z += v.z; acc.w += v.w;
  }
  red[t] = acc;
  __syncthreads();
  if (t < 16) {
    float4 a = red[t];
#pragma unroll
    for (int g = 1; g < 16; ++g) {
      const float4 o = red[g * 16 + t];
      a.x += o.x; a.y += o.y; a.z += o.z; a.w += o.w;
    }
    const float inv = 1.0f / (float)S_N;
    xm[t * 4 + 0] = a.x * inv; xm[t * 4 + 1] = a.y * inv;
    xm[t * 4 + 2] = a.z * inv; xm[t * 4 + 3] = a.w * inv;
  }
  __syncthreads();
  // projection: thread t computes xe[b][t]
  float p = bias[t];
#pragma unroll
  for (int k4 = 0; k4 < F_N / 4; ++k4) {
    const float4 wv = *(const float4*)&W[(size_t)t * F_N + k4 * 4];
    const float4 xv = *(const float4*)&xm[k4 * 4];
    p = fmaf(wv.x, xv.x, p);
    p = fmaf(wv.y, xv.y, p);
    p = fmaf(wv.z, xv.z, p);
    p = fmaf(wv.w, xv.w, p);
  }
  xe[(size_t)b * D_N + t] = p;
}

// ---------------- K2: score = 0.5*||reg_r||^2 - xe.reg_r ; per-tile argmin ----------------
// 8 waves, 8x8 thread tile. A (xe) via wave-uniform scalar loads (SGPR operand in FMA),
// B (regT) via LDS double-buffer. LDS cost: 16 ds_read_b128 per 1024 FMA-instr -> VALU-bound.
__global__ __launch_bounds__(512, 4) void k_score(const float* __restrict__ xe,
                                                  const float* __restrict__ regT,
                                                  const float* __restrict__ rsqh,
                                                  float* __restrict__ pval,
                                                  int* __restrict__ pidx) {
  __shared__ __align__(16) float lB[2][CS_KC * CS_CW];  // 2 x 16 KB (regT chunk [k][c])
  const int t = threadIdx.x;
  const int w = t >> 6;                                    // 0..7
  const int wu = __builtin_amdgcn_readfirstlane(w);        // wave-uniform for codegen
  const int lane = t & 63;
  const int jb = blockIdx.x;            // col tile 0..7
  const int bm0 = blockIdx.y * CS_BM;   // row base
  const int c0 = lane * 4;              // col base (plus +256 half)
  const float* xeu = xe + (size_t)(bm0 + wu * 8) * D_N;  // uniform base -> s_load path

  float acc[8][8];  // [row][col]; cols 0-3 = c0 block, 4-7 = c0+256 block
#pragma unroll
  for (int mm = 0; mm < 8; ++mm)
#pragma unroll
    for (int cc = 0; cc < 8; ++cc) acc[mm][cc] = 0.f;

  auto stage = [&](int ch, int nb) {
    const int k0 = ch * CS_KC;
    // B chunk [8][512] = 16 KB = 16 lane-1KB loads; wave w takes q = 2w, 2w+1
#pragma unroll
    for (int i = 0; i < 2; ++i) {
      const int q = w * 2 + i;
      const int row = q >> 1, half = q & 1;
      gld_lds16(&regT[(size_t)(k0 + row) * R_N + jb * CS_CW + half * 256 + lane * 4],
                &lB[nb][row * CS_CW + half * 256 + lane * 4]);
    }
  };

  stage(0, 0);
  __syncthreads();
  int buf = 0;
  for (int ch = 0; ch < CS_NCH; ++ch) {
    if (ch + 1 < CS_NCH) stage(ch + 1, buf ^ 1);
    const float* Bc = lB[buf];
    const int k0 = ch * CS_KC;
#pragma unroll
    for (int ks = 0; ks < 2; ++ks) {  // two 4-k steps per chunk
      float b0[4][4], b1[4][4];
#pragma unroll
      for (int j = 0; j < 4; ++j) {
        const float4 v0 = *(const float4*)&Bc[(ks * 4 + j) * CS_CW + c0];
        const float4 v1 = *(const float4*)&Bc[(ks * 4 + j) * CS_CW + c0 + 256];
        b0[j][0] = v0.x; b0[j][1] = v0.y; b0[j][2] = v0.z; b0[j][3] = v0.w;
        b1[j][0] = v1.x; b1[j][1] = v1.y; b1[j][2] = v1.z; b1[j][3] = v1.w;
      }
#pragma unroll
      for (int mm = 0; mm < 8; ++mm) {
        // wave-uniform scalar load (SGPRs; free for the vector pipes)
        const float4 a4 = *(const float4*)&xeu[mm * D_N + k0 + ks * 4];
        const float av[4] = {a4.x, a4.y, a4.z, a4.w};
#pragma unroll
        for (int j = 0; j < 4; ++j)
#pragma unroll
          for (int cc = 0; cc < 4; ++cc) {
            acc[mm][cc]     = fmaf(av[j], b0[j][cc], acc[mm][cc]);
            acc[mm][4 + cc] = fmaf(av[j], b1[j][cc], acc[mm][4 + cc]);
          }
      }
    }
    __syncthreads();
    buf ^= 1;
  }

  // epilogue: score = 0.5*||reg||^2 - dot ; per-row argmin over this col tile
  const float4 q0 = *(const float4*)&rsqh[jb * CS_CW + c0];
  const float4 q1 = *(const float4*)&rsqh[jb * CS_CW + c0 + 256];
  const float r0a[4] = {q0.x, q0.y, q0.z, q0.w};
  const float r1a[4] = {q1.x, q1.y, q1.z, q1.w};
  const int cbase = jb * CS_CW + c0;
#pragma unroll
  for (int mm = 0; mm < 8; ++mm) {
    float bv = r0a[0] - acc[mm][0];
    int bi = cbase;
#pragma unroll
    for (int cc = 1; cc < 4; ++cc) {  // ascending index, strict < -> lowest idx wins
      const float s = r0a[cc] - acc[mm][cc];
      if (s < bv) { bv = s; bi = cbase + cc; }
    }
#pragma unroll
    for (int cc = 0; cc < 4; ++cc) {
      const float s = r1a[cc] - acc[mm][4 + cc];
      if (s < bv) { bv = s; bi = cbase + 256 + cc; }
    }
#pragma unroll
    for (int m = 32; m >= 1; m >>= 1) {
      const float ov = __shfl_xor(bv, m);
      const int oi = __shfl_xor(bi, m);
      if (ov < bv || (ov == bv && oi < bi)) { bv = ov; bi = oi; }
    }
    if (lane == 0) {
      pval[(size_t)(bm0 + wu * 8 + mm) * CS_NJ + jb] = bv;
      pidx[(size_t)(bm0 + wu * 8 + mm) * CS_NJ + jb] = bi;
    }
  }
}

// ---------------- K3: reduce partials, gather codebook row, write Xd + per-b loss ----------------
__global__ __launch_bounds__(256) void k_final(const float* __restrict__ reg,
                                               const float* __restrict__ xe,
                                               const float* __restrict__ pval,
                                               const int* __restrict__ pidx,
                                               float* __restrict__ out,
                                               float* __restrict__ lossArr) {
  const int b = blockIdx.x;
  const int t = threadIdx.x;
  const int lane = t & 63;
  const int w = t >> 6;
  // argmin over 8 tile partials (every 8-lane group does the same reduce)
  float bv = pval[(size_t)b * CS_NJ + (t & 7)];
  int bi = pidx[(size_t)b * CS_NJ + (t & 7)];
#pragma unroll
  for (int m = 4; m >= 1; m >>= 1) {
    const float ov = __shfl_xor(bv, m);
    const int oi = __shfl_xor(bi, m);
    if (ov < bv || (ov == bv && oi < bi)) { bv = ov; bi = oi; }
  }
  const int d4 = lane * 4;
  const float4 sel = *(const float4*)&reg[(size_t)bi * D_N + d4];
  // tile selected row across T_N tokens (1 KB contiguous per wave-instr)
#pragma unroll
  for (int tt0 = 0; tt0 < T_N / 4; ++tt0) {
    const int tt = tt0 * 4 + w;
    *(float4*)&out[(size_t)b * (T_N * D_N) + (size_t)tt * D_N + d4] = sel;
  }
  // per-b loss partial (each wave computes the full row sum; wave0 writes)
  const float4 xv = *(const float4*)&xe[(size_t)b * D_N + d4];
  const float ex = xv.x - sel.x, ey = xv.y - sel.y, ez = xv.z - sel.z, ew = xv.w - sel.w;
  float p = ex * ex + ey * ey + ez * ez + ew * ew;
#pragma unroll
  for (int m = 32; m >= 1; m >>= 1) p += __shfl_xor(p, m);
  if (t == 0) lossArr[b] = p;
}

// ---------------- K4: loss = mean over B ----------------
__global__ __launch_bounds__(256) void k_loss(const float* __restrict__ lossArr,
                                              float* __restrict__ out) {
  __shared__ float ws4[4];
  const int t = threadIdx.x;
  float s = 0.f;
  for (int i = t; i < B_N; i += 256) s += lossArr[i];
#pragma unroll
  for (int m = 32; m >= 1; m >>= 1) s += __shfl_xor(s, m);
  if ((t & 63) == 0) ws4[t >> 6] = s;
  __syncthreads();
  if (t == 0)
    out[(size_t)B_N * T_N * D_N] = (ws4[0] + ws4[1] + ws4[2] + ws4[3]) / (float)B_N;
}

extern "C" void kernel_launch(void* const* d_in, const int* in_sizes, int n_in,
                              void* d_out, int out_size, void* d_ws, size_t ws_size,
                              hipStream_t stream) {
  const float* x    = (const float*)d_in[0];
  const float* W    = (const float*)d_in[1];
  const float* bias = (const float*)d_in[2];
  const float* reg  = (const float*)d_in[3];
  float* out = (float*)d_out;
  float* ws  = (float*)d_ws;

  // workspace layout (floats): all regions fully rewritten every call
  float* xe      = ws;                            // 8192*256
  float* regT    = xe + (size_t)B_N * D_N;        // 256*4096
  float* rsqh    = regT + (size_t)D_N * R_N;      // 4096
  float* pval    = rsqh + R_N;                    // 8192*8
  int*   pidx    = (int*)(pval + (size_t)B_N * CS_NJ);  // 8192*8
  float* lossArr = (float*)pidx + (size_t)B_N * CS_NJ;  // 8192

  k_rsq<<<dim3(R_N / 4), dim3(256), 0, stream>>>(reg, rsqh);
  k_transpose<<<dim3(R_N / 64, D_N / 64), dim3(256), 0, stream>>>(reg, regT);
  k_meanproj<<<dim3(B_N), dim3(256), 0, stream>>>(x, W, bias, xe);
  k_score<<<dim3(CS_NJ, B_N / CS_BM), dim3(512), 0, stream>>>(xe, regT, rsqh, pval, pidx);
  k_final<<<dim3(B_N), dim3(256), 0, stream>>>(reg, xe, pval, pidx, out, lossArr);
  k_loss<<<dim3(1), dim3(256), 0, stream>>>(lossArr, out);
}

// Round 6
// 434.035 us; speedup vs baseline: 1.3959x; 1.1204x over previous
//
#include <hip/hip_runtime.h>
#include <hip/hip_bf16.h>

typedef unsigned short ushortT;
typedef __attribute__((ext_vector_type(8))) short v8s;
typedef __attribute__((ext_vector_type(4))) float v4f;

// Problem sizes (fixed by reference)
#define B_N   8192
#define S_N   512
#define F_N   64
#define R_N   4096
#define D_N   256
#define T_N   16

#define NJ    16   // col-tiles of 256 -> pval/pidx width

__device__ __forceinline__ ushortT f2bf(float x) {
  __hip_bfloat16 b = __float2bfloat16(x);
  return *(ushortT*)&b;
}
__device__ __forceinline__ float bf2f(ushortT u) {
  __hip_bfloat16 b = *(__hip_bfloat16*)&u;
  return __bfloat162float(b);
}

// ---------------- K0: reg -> regH/regL bf16 split + rsqh = 0.5*||reg_r||^2 ----------------
__global__ __launch_bounds__(256) void k_prep_reg(const float* __restrict__ reg,
                                                  ushortT* __restrict__ regH,
                                                  ushortT* __restrict__ regL,
                                                  float* __restrict__ rsqh) {
  const int t = threadIdx.x;
  const int lane = t & 63;
  const int r = blockIdx.x * 4 + (t >> 6);
  const float4 v = *(const float4*)&reg[(size_t)r * D_N + lane * 4];
  short4 h, l;
  h.x = f2bf(v.x); l.x = f2bf(v.x - bf2f(h.x));
  h.y = f2bf(v.y); l.y = f2bf(v.y - bf2f(h.y));
  h.z = f2bf(v.z); l.z = f2bf(v.z - bf2f(h.z));
  h.w = f2bf(v.w); l.w = f2bf(v.w - bf2f(h.w));
  *(short4*)&regH[(size_t)r * D_N + lane * 4] = h;
  *(short4*)&regL[(size_t)r * D_N + lane * 4] = l;
  float s = v.x * v.x + v.y * v.y + v.z * v.z + v.w * v.w;
#pragma unroll
  for (int m = 32; m >= 1; m >>= 1) s += __shfl_xor(s, m);
  if (lane == 0) rsqh[r] = 0.5f * s;
}

// ---------------- K1: temporal mean + projection -> xe (fp32) + xeH/xeL (bf16 split) ----
__global__ __launch_bounds__(256) void k_meanproj(const float* __restrict__ x,
                                                  const float* __restrict__ W,
                                                  const float* __restrict__ bias,
                                                  float* __restrict__ xe,
                                                  ushortT* __restrict__ xeH,
                                                  ushortT* __restrict__ xeL) {
  __shared__ __align__(16) float4 red[256];
  __shared__ __align__(16) float xm[F_N];
  const int b = blockIdx.x;
  const int t = threadIdx.x;
  const float* xb = x + (size_t)b * (S_N * F_N);
  const int sg = t >> 4;         // 0..15 (s subgroup)
  const int f4 = (t & 15) * 4;   // feature base
  float4 acc = make_float4(0.f, 0.f, 0.f, 0.f);
#pragma unroll 4
  for (int s = sg; s < S_N; s += 16) {
    const float4 v = *(const float4*)&xb[s * F_N + f4];
    acc.x += v.x; acc.y += v.y; acc.z += v.z; acc.w += v.w;
  }
  red[t] = acc;
  __syncthreads();
  if (t < 16) {
    float4 a = red[t];
#pragma unroll
    for (int g = 1; g < 16; ++g) {
      const float4 o = red[g * 16 + t];
      a.x += o.x; a.y += o.y; a.z += o.z; a.w += o.w;
    }
    const float inv = 1.0f / (float)S_N;
    xm[t * 4 + 0] = a.x * inv; xm[t * 4 + 1] = a.y * inv;
    xm[t * 4 + 2] = a.z * inv; xm[t * 4 + 3] = a.w * inv;
  }
  __syncthreads();
  // projection: thread t computes xe[b][t]
  float p = bias[t];
#pragma unroll
  for (int k4 = 0; k4 < F_N / 4; ++k4) {
    const float4 wv = *(const float4*)&W[(size_t)t * F_N + k4 * 4];
    const float4 xv = *(const float4*)&xm[k4 * 4];
    p = fmaf(wv.x, xv.x, p);
    p = fmaf(wv.y, xv.y, p);
    p = fmaf(wv.z, xv.z, p);
    p = fmaf(wv.w, xv.w, p);
  }
  xe[(size_t)b * D_N + t] = p;
  const ushortT hh = f2bf(p);
  const ushortT ll = f2bf(p - bf2f(hh));
  xeH[(size_t)b * D_N + t] = hh;
  xeL[(size_t)b * D_N + t] = ll;
}

// ---------------- K2: score GEMM on matrix cores (3-pass bf16 split), argmin ----------
// Block: 4 waves = 64 rows x 256 cols; wave tile 64x64 via 4x4 16x16x32 frags.
// dot exact to ~5e-9 (hh+hl+lh, fp32 accum); score = 0.5*||reg||^2 - dot.
__global__ __launch_bounds__(256, 3) void k_score(const ushortT* __restrict__ xeH,
                                                  const ushortT* __restrict__ xeL,
                                                  const ushortT* __restrict__ regH,
                                                  const ushortT* __restrict__ regL,
                                                  const float* __restrict__ rsqh,
                                                  float* __restrict__ pval,
                                                  int* __restrict__ pidx) {
  __shared__ float sval[4][64];
  __shared__ int   sidx[4][64];
  const int t = threadIdx.x;
  const int w = t >> 6;
  const int lane = t & 63;
  const int row16 = lane & 15;   // A-row / B-col within fragment
  const int kg = lane >> 4;      // k-group (holds k = kg*8 .. kg*8+7)
  const int jb = blockIdx.x;               // col tile 0..15 (256 cols)
  const int bm0 = blockIdx.y * 64;         // row base
  const int n0 = jb * 256 + w * 64;        // this wave's col base

  const ushortT* Ah = xeH + (size_t)(bm0 + row16) * D_N + kg * 8;
  const ushortT* Al = xeL + (size_t)(bm0 + row16) * D_N + kg * 8;
  const ushortT* Bh = regH + (size_t)(n0 + row16) * D_N + kg * 8;
  const ushortT* Bl = regL + (size_t)(n0 + row16) * D_N + kg * 8;

  v4f acc[4][4];
#pragma unroll
  for (int mi = 0; mi < 4; ++mi)
#pragma unroll
    for (int ni = 0; ni < 4; ++ni) acc[mi][ni] = (v4f){0.f, 0.f, 0.f, 0.f};

#pragma unroll 2
  for (int k0 = 0; k0 < D_N; k0 += 32) {
    v8s ah[4], al[4], bh[4], bl[4];
#pragma unroll
    for (int i = 0; i < 4; ++i) {
      ah[i] = *(const v8s*)&Ah[i * 16 * D_N + k0];
      al[i] = *(const v8s*)&Al[i * 16 * D_N + k0];
      bh[i] = *(const v8s*)&Bh[i * 16 * D_N + k0];
      bl[i] = *(const v8s*)&Bl[i * 16 * D_N + k0];
    }
#pragma unroll
    for (int mi = 0; mi < 4; ++mi)
#pragma unroll
      for (int ni = 0; ni < 4; ++ni) {
        acc[mi][ni] = __builtin_amdgcn_mfma_f32_16x16x32_bf16(ah[mi], bh[ni], acc[mi][ni], 0, 0, 0);
        acc[mi][ni] = __builtin_amdgcn_mfma_f32_16x16x32_bf16(ah[mi], bl[ni], acc[mi][ni], 0, 0, 0);
        acc[mi][ni] = __builtin_amdgcn_mfma_f32_16x16x32_bf16(al[mi], bh[ni], acc[mi][ni], 0, 0, 0);
      }
  }

  // rsqh for this lane's 4 candidate cols (ni-indexed); cols ascend with ni
  float rq[4];
#pragma unroll
  for (int ni = 0; ni < 4; ++ni) rq[ni] = 0.5f * 0.f + rsqh[n0 + ni * 16 + row16];

  // per-(mi,j) best over ni, then reduce across the 16 lanes of this k-group
#pragma unroll
  for (int mi = 0; mi < 4; ++mi) {
#pragma unroll
    for (int j = 0; j < 4; ++j) {
      float bv = rq[0] - acc[mi][0][j];
      int bi = n0 + row16;
#pragma unroll
      for (int ni = 1; ni < 4; ++ni) {  // ascending col, strict < -> lowest idx
        const float s = rq[ni] - acc[mi][ni][j];
        if (s < bv) { bv = s; bi = n0 + ni * 16 + row16; }
      }
#pragma unroll
      for (int m = 8; m >= 1; m >>= 1) {  // reduce cols across 16-lane group
        const float ov = __shfl_xor(bv, m);
        const int oi = __shfl_xor(bi, m);
        if (ov < bv || (ov == bv && oi < bi)) { bv = ov; bi = oi; }
      }
      if (row16 == 0) {
        const int row_local = mi * 16 + kg * 4 + j;  // D row = (lane>>4)*4 + reg_idx
        sval[w][row_local] = bv;
        sidx[w][row_local] = bi;
      }
    }
  }
  __syncthreads();
  // combine the 4 waves' col-strips (ascending w = ascending cols)
  if (t < 64) {
    float bv = sval[0][t];
    int bi = sidx[0][t];
#pragma unroll
    for (int ww = 1; ww < 4; ++ww) {
      const float ov = sval[ww][t];
      const int oi = sidx[ww][t];
      if (ov < bv || (ov == bv && oi < bi)) { bv = ov; bi = oi; }
    }
    pval[(size_t)(bm0 + t) * NJ + jb] = bv;
    pidx[(size_t)(bm0 + t) * NJ + jb] = bi;
  }
}

// ---------------- K3: reduce partials, gather codebook row, write Xd + per-b loss ------
__global__ __launch_bounds__(256) void k_final(const float* __restrict__ reg,
                                               const float* __restrict__ xe,
                                               const float* __restrict__ pval,
                                               const int* __restrict__ pidx,
                                               float* __restrict__ out,
                                               float* __restrict__ lossArr) {
  const int b = blockIdx.x;
  const int t = threadIdx.x;
  const int lane = t & 63;
  const int w = t >> 6;
  // argmin over 16 tile partials (every 16-lane group does the same reduce)
  float bv = pval[(size_t)b * NJ + (t & 15)];
  int bi = pidx[(size_t)b * NJ + (t & 15)];
#pragma unroll
  for (int m = 8; m >= 1; m >>= 1) {
    const float ov = __shfl_xor(bv, m);
    const int oi = __shfl_xor(bi, m);
    if (ov < bv || (ov == bv && oi < bi)) { bv = ov; bi = oi; }
  }
  const int d4 = lane * 4;
  const float4 sel = *(const float4*)&reg[(size_t)bi * D_N + d4];
#pragma unroll
  for (int tt0 = 0; tt0 < T_N / 4; ++tt0) {
    const int tt = tt0 * 4 + w;
    *(float4*)&out[(size_t)b * (T_N * D_N) + (size_t)tt * D_N + d4] = sel;
  }
  const float4 xv = *(const float4*)&xe[(size_t)b * D_N + d4];
  const float ex = xv.x - sel.x, ey = xv.y - sel.y, ez = xv.z - sel.z, ew = xv.w - sel.w;
  float p = ex * ex + ey * ey + ez * ez + ew * ew;
#pragma unroll
  for (int m = 32; m >= 1; m >>= 1) p += __shfl_xor(p, m);
  if (t == 0) lossArr[b] = p;
}

// ---------------- K4: loss = mean over B ----------------
__global__ __launch_bounds__(256) void k_loss(const float* __restrict__ lossArr,
                                              float* __restrict__ out) {
  __shared__ float ws4[4];
  const int t = threadIdx.x;
  float s = 0.f;
  for (int i = t; i < B_N; i += 256) s += lossArr[i];
#pragma unroll
  for (int m = 32; m >= 1; m >>= 1) s += __shfl_xor(s, m);
  if ((t & 63) == 0) ws4[t >> 6] = s;
  __syncthreads();
  if (t == 0)
    out[(size_t)B_N * T_N * D_N] = (ws4[0] + ws4[1] + ws4[2] + ws4[3]) / (float)B_N;
}

extern "C" void kernel_launch(void* const* d_in, const int* in_sizes, int n_in,
                              void* d_out, int out_size, void* d_ws, size_t ws_size,
                              hipStream_t stream) {
  const float* x    = (const float*)d_in[0];
  const float* W    = (const float*)d_in[1];
  const float* bias = (const float*)d_in[2];
  const float* reg  = (const float*)d_in[3];
  float* out = (float*)d_out;
  float* ws  = (float*)d_ws;

  // workspace layout: all regions fully rewritten every call (~21 MB)
  float*   xe   = ws;                                   // 8192*256 f32   (8 MB)
  ushortT* xeH  = (ushortT*)(xe + (size_t)B_N * D_N);   // 8192*256 bf16  (4 MB)
  ushortT* xeL  = xeH + (size_t)B_N * D_N;              // 4 MB
  ushortT* regH = xeL + (size_t)B_N * D_N;              // 4096*256 bf16  (2 MB)
  ushortT* regL = regH + (size_t)R_N * D_N;             // 2 MB
  float*   rsqh = (float*)(regL + (size_t)R_N * D_N);   // 4096
  float*   pval = rsqh + R_N;                           // 8192*16
  int*     pidx = (int*)(pval + (size_t)B_N * NJ);      // 8192*16
  float* lossArr = (float*)pidx + (size_t)B_N * NJ;     // 8192

  k_prep_reg<<<dim3(R_N / 4), dim3(256), 0, stream>>>(reg, regH, regL, rsqh);
  k_meanproj<<<dim3(B_N), dim3(256), 0, stream>>>(x, W, bias, xe, xeH, xeL);
  k_score<<<dim3(NJ, B_N / 64), dim3(256), 0, stream>>>(xeH, xeL, regH, regL, rsqh, pval, pidx);
  k_final<<<dim3(B_N), dim3(256), 0, stream>>>(reg, xe, pval, pidx, out, lossArr);
  k_loss<<<dim3(1), dim3(256), 0, stream>>>(lossArr, out);
}

// Round 7
// 429.466 us; speedup vs baseline: 1.4107x; 1.0106x over previous
//
#include <hip/hip_runtime.h>
#include <hip/hip_bf16.h>

typedef unsigned short ushortT;
typedef __attribute__((ext_vector_type(8))) short v8s;
typedef __attribute__((ext_vector_type(4))) float v4f;

// Problem sizes (fixed by reference)
#define B_N   8192
#define S_N   512
#define F_N   64
#define R_N   4096
#define D_N   256
#define T_N   16

#define NJ    16   // col-tiles of 256 -> pval/pidx width

__device__ __forceinline__ ushortT f2bf(float x) {
  __hip_bfloat16 b = __float2bfloat16(x);
  return *(ushortT*)&b;
}
__device__ __forceinline__ float bf2f(ushortT u) {
  __hip_bfloat16 b = *(__hip_bfloat16*)&u;
  return __bfloat162float(b);
}

// ---------------- K0: reg -> regH/regL bf16 split + rsqh = 0.5*||reg_r||^2 ----------------
__global__ __launch_bounds__(256) void k_prep_reg(const float* __restrict__ reg,
                                                  ushortT* __restrict__ regH,
                                                  ushortT* __restrict__ regL,
                                                  float* __restrict__ rsqh) {
  const int t = threadIdx.x;
  const int lane = t & 63;
  const int r = blockIdx.x * 4 + (t >> 6);
  const float4 v = *(const float4*)&reg[(size_t)r * D_N + lane * 4];
  short4 h, l;
  h.x = f2bf(v.x); l.x = f2bf(v.x - bf2f(h.x));
  h.y = f2bf(v.y); l.y = f2bf(v.y - bf2f(h.y));
  h.z = f2bf(v.z); l.z = f2bf(v.z - bf2f(h.z));
  h.w = f2bf(v.w); l.w = f2bf(v.w - bf2f(h.w));
  *(short4*)&regH[(size_t)r * D_N + lane * 4] = h;
  *(short4*)&regL[(size_t)r * D_N + lane * 4] = l;
  float s = v.x * v.x + v.y * v.y + v.z * v.z + v.w * v.w;
#pragma unroll
  for (int m = 32; m >= 1; m >>= 1) s += __shfl_xor(s, m);
  if (lane == 0) rsqh[r] = 0.5f * s;
}

// ---------------- K1: temporal mean + projection -> xe (fp32) + xeH/xeL (bf16 split) ----
__global__ __launch_bounds__(256) void k_meanproj(const float* __restrict__ x,
                                                  const float* __restrict__ W,
                                                  const float* __restrict__ bias,
                                                  float* __restrict__ xe,
                                                  ushortT* __restrict__ xeH,
                                                  ushortT* __restrict__ xeL) {
  __shared__ __align__(16) float4 red[256];
  __shared__ __align__(16) float xm[F_N];
  const int b = blockIdx.x;
  const int t = threadIdx.x;
  const float* xb = x + (size_t)b * (S_N * F_N);
  const int sg = t >> 4;         // 0..15 (s subgroup)
  const int f4 = (t & 15) * 4;   // feature base
  float4 acc = make_float4(0.f, 0.f, 0.f, 0.f);
#pragma unroll 4
  for (int s = sg; s < S_N; s += 16) {
    const float4 v = *(const float4*)&xb[s * F_N + f4];
    acc.x += v.x; acc.y += v.y; acc.z += v.z; acc.w += v.w;
  }
  red[t] = acc;
  __syncthreads();
  if (t < 16) {
    float4 a = red[t];
#pragma unroll
    for (int g = 1; g < 16; ++g) {
      const float4 o = red[g * 16 + t];
      a.x += o.x; a.y += o.y; a.z += o.z; a.w += o.w;
    }
    const float inv = 1.0f / (float)S_N;
    xm[t * 4 + 0] = a.x * inv; xm[t * 4 + 1] = a.y * inv;
    xm[t * 4 + 2] = a.z * inv; xm[t * 4 + 3] = a.w * inv;
  }
  __syncthreads();
  // projection: thread t computes xe[b][t]
  float p = bias[t];
#pragma unroll
  for (int k4 = 0; k4 < F_N / 4; ++k4) {
    const float4 wv = *(const float4*)&W[(size_t)t * F_N + k4 * 4];
    const float4 xv = *(const float4*)&xm[k4 * 4];
    p = fmaf(wv.x, xv.x, p);
    p = fmaf(wv.y, xv.y, p);
    p = fmaf(wv.z, xv.z, p);
    p = fmaf(wv.w, xv.w, p);
  }
  xe[(size_t)b * D_N + t] = p;
  const ushortT hh = f2bf(p);
  const ushortT ll = f2bf(p - bf2f(hh));
  xeH[(size_t)b * D_N + t] = hh;
  xeL[(size_t)b * D_N + t] = ll;
}

// ---------------- K2: score GEMM on matrix cores (3-pass bf16 split), argmin ----------
// Block: 4 waves = 64 rows x 256 cols; wave tile 64x64 via 4x4 16x16x32 frags.
// B-frags double-buffered in registers (prefetch next k-chunk); A-frags loaded per-mi.
// Live VGPR ~150 (B dbuf 64 + A 8 + acc 64 + addr) -> no spill under the 256 cap.
__global__ __launch_bounds__(256, 2) void k_score(const ushortT* __restrict__ xeH,
                                                  const ushortT* __restrict__ xeL,
                                                  const ushortT* __restrict__ regH,
                                                  const ushortT* __restrict__ regL,
                                                  const float* __restrict__ rsqh,
                                                  float* __restrict__ pval,
                                                  int* __restrict__ pidx) {
  __shared__ float sval[4][64];
  __shared__ int   sidx[4][64];
  const int t = threadIdx.x;
  const int w = t >> 6;
  const int lane = t & 63;
  const int row16 = lane & 15;   // A-row / B-col within fragment
  const int kg = lane >> 4;      // k-group (holds k = kg*8 .. kg*8+7)
  const int jb = blockIdx.x;               // col tile 0..15 (256 cols)
  const int bm0 = blockIdx.y * 64;         // row base
  const int n0 = jb * 256 + w * 64;        // this wave's col base

  const ushortT* Ah = xeH + (size_t)(bm0 + row16) * D_N + kg * 8;
  const ushortT* Al = xeL + (size_t)(bm0 + row16) * D_N + kg * 8;
  const ushortT* Bh = regH + (size_t)(n0 + row16) * D_N + kg * 8;
  const ushortT* Bl = regL + (size_t)(n0 + row16) * D_N + kg * 8;

  v4f acc[4][4];
#pragma unroll
  for (int mi = 0; mi < 4; ++mi)
#pragma unroll
    for (int ni = 0; ni < 4; ++ni) acc[mi][ni] = (v4f){0.f, 0.f, 0.f, 0.f};

  v8s bh[2][4], bl[2][4];
#pragma unroll
  for (int i = 0; i < 4; ++i) {  // prefetch k-chunk 0
    bh[0][i] = *(const v8s*)&Bh[i * 16 * D_N];
    bl[0][i] = *(const v8s*)&Bl[i * 16 * D_N];
  }

  for (int k0 = 0; k0 < D_N; k0 += 32) {
    const int cur = (k0 >> 5) & 1;
    if (k0 + 32 < D_N) {
#pragma unroll
      for (int i = 0; i < 4; ++i) {  // prefetch next k-chunk while computing this one
        bh[cur ^ 1][i] = *(const v8s*)&Bh[i * 16 * D_N + k0 + 32];
        bl[cur ^ 1][i] = *(const v8s*)&Bl[i * 16 * D_N + k0 + 32];
      }
    }
#pragma unroll
    for (int mi = 0; mi < 4; ++mi) {
      const v8s ah = *(const v8s*)&Ah[mi * 16 * D_N + k0];
      const v8s al = *(const v8s*)&Al[mi * 16 * D_N + k0];
#pragma unroll
      for (int ni = 0; ni < 4; ++ni) {
        acc[mi][ni] = __builtin_amdgcn_mfma_f32_16x16x32_bf16(ah, bh[cur][ni], acc[mi][ni], 0, 0, 0);
        acc[mi][ni] = __builtin_amdgcn_mfma_f32_16x16x32_bf16(ah, bl[cur][ni], acc[mi][ni], 0, 0, 0);
        acc[mi][ni] = __builtin_amdgcn_mfma_f32_16x16x32_bf16(al, bh[cur][ni], acc[mi][ni], 0, 0, 0);
      }
    }
  }

  // rsqh for this lane's 4 candidate cols (ni-indexed); cols ascend with ni
  float rq[4];
#pragma unroll
  for (int ni = 0; ni < 4; ++ni) rq[ni] = rsqh[n0 + ni * 16 + row16];

  // per-(mi,j) best over ni, then reduce across the 16 lanes of this k-group
#pragma unroll
  for (int mi = 0; mi < 4; ++mi) {
#pragma unroll
    for (int j = 0; j < 4; ++j) {
      float bv = rq[0] - acc[mi][0][j];
      int bi = n0 + row16;
#pragma unroll
      for (int ni = 1; ni < 4; ++ni) {  // ascending col, strict < -> lowest idx
        const float s = rq[ni] - acc[mi][ni][j];
        if (s < bv) { bv = s; bi = n0 + ni * 16 + row16; }
      }
#pragma unroll
      for (int m = 8; m >= 1; m >>= 1) {  // reduce cols across 16-lane group
        const float ov = __shfl_xor(bv, m);
        const int oi = __shfl_xor(bi, m);
        if (ov < bv || (ov == bv && oi < bi)) { bv = ov; bi = oi; }
      }
      if (row16 == 0) {
        const int row_local = mi * 16 + kg * 4 + j;  // D row = (lane>>4)*4 + reg_idx
        sval[w][row_local] = bv;
        sidx[w][row_local] = bi;
      }
    }
  }
  __syncthreads();
  // combine the 4 waves' col-strips (ascending w = ascending cols)
  if (t < 64) {
    float bv = sval[0][t];
    int bi = sidx[0][t];
#pragma unroll
    for (int ww = 1; ww < 4; ++ww) {
      const float ov = sval[ww][t];
      const int oi = sidx[ww][t];
      if (ov < bv || (ov == bv && oi < bi)) { bv = ov; bi = oi; }
    }
    pval[(size_t)(bm0 + t) * NJ + jb] = bv;
    pidx[(size_t)(bm0 + t) * NJ + jb] = bi;
  }
}

// ---------------- K3: reduce partials, gather codebook row, write Xd + per-b loss ------
__global__ __launch_bounds__(256) void k_final(const float* __restrict__ reg,
                                               const float* __restrict__ xe,
                                               const float* __restrict__ pval,
                                               const int* __restrict__ pidx,
                                               float* __restrict__ out,
                                               float* __restrict__ lossArr) {
  const int b = blockIdx.x;
  const int t = threadIdx.x;
  const int lane = t & 63;
  const int w = t >> 6;
  // argmin over 16 tile partials (every 16-lane group does the same reduce)
  float bv = pval[(size_t)b * NJ + (t & 15)];
  int bi = pidx[(size_t)b * NJ + (t & 15)];
#pragma unroll
  for (int m = 8; m >= 1; m >>= 1) {
    const float ov = __shfl_xor(bv, m);
    const int oi = __shfl_xor(bi, m);
    if (ov < bv || (ov == bv && oi < bi)) { bv = ov; bi = oi; }
  }
  const int d4 = lane * 4;
  const float4 sel = *(const float4*)&reg[(size_t)bi * D_N + d4];
#pragma unroll
  for (int tt0 = 0; tt0 < T_N / 4; ++tt0) {
    const int tt = tt0 * 4 + w;
    *(float4*)&out[(size_t)b * (T_N * D_N) + (size_t)tt * D_N + d4] = sel;
  }
  const float4 xv = *(const float4*)&xe[(size_t)b * D_N + d4];
  const float ex = xv.x - sel.x, ey = xv.y - sel.y, ez = xv.z - sel.z, ew = xv.w - sel.w;
  float p = ex * ex + ey * ey + ez * ez + ew * ew;
#pragma unroll
  for (int m = 32; m >= 1; m >>= 1) p += __shfl_xor(p, m);
  if (t == 0) lossArr[b] = p;
}

// ---------------- K4: loss = mean over B ----------------
__global__ __launch_bounds__(256) void k_loss(const float* __restrict__ lossArr,
                                              float* __restrict__ out) {
  __shared__ float ws4[4];
  const int t = threadIdx.x;
  float s = 0.f;
  for (int i = t; i < B_N; i += 256) s += lossArr[i];
#pragma unroll
  for (int m = 32; m >= 1; m >>= 1) s += __shfl_xor(s, m);
  if ((t & 63) == 0) ws4[t >> 6] = s;
  __syncthreads();
  if (t == 0)
    out[(size_t)B_N * T_N * D_N] = (ws4[0] + ws4[1] + ws4[2] + ws4[3]) / (float)B_N;
}

extern "C" void kernel_launch(void* const* d_in, const int* in_sizes, int n_in,
                              void* d_out, int out_size, void* d_ws, size_t ws_size,
                              hipStream_t stream) {
  const float* x    = (const float*)d_in[0];
  const float* W    = (const float*)d_in[1];
  const float* bias = (const float*)d_in[2];
  const float* reg  = (const float*)d_in[3];
  float* out = (float*)d_out;
  float* ws  = (float*)d_ws;

  // workspace layout: all regions fully rewritten every call (~21 MB)
  float*   xe   = ws;                                   // 8192*256 f32   (8 MB)
  ushortT* xeH  = (ushortT*)(xe + (size_t)B_N * D_N);   // 8192*256 bf16  (4 MB)
  ushortT* xeL  = xeH + (size_t)B_N * D_N;              // 4 MB
  ushortT* regH = xeL + (size_t)B_N * D_N;              // 4096*256 bf16  (2 MB)
  ushortT* regL = regH + (size_t)R_N * D_N;             // 2 MB
  float*   rsqh = (float*)(regL + (size_t)R_N * D_N);   // 4096
  float*   pval = rsqh + R_N;                           // 8192*16
  int*     pidx = (int*)(pval + (size_t)B_N * NJ);      // 8192*16
  float* lossArr = (float*)pidx + (size_t)B_N * NJ;     // 8192

  k_prep_reg<<<dim3(R_N / 4), dim3(256), 0, stream>>>(reg, regH, regL, rsqh);
  k_meanproj<<<dim3(B_N), dim3(256), 0, stream>>>(x, W, bias, xe, xeH, xeL);
  k_score<<<dim3(NJ, B_N / 64), dim3(256), 0, stream>>>(xeH, xeL, regH, regL, rsqh, pval, pidx);
  k_final<<<dim3(B_N), dim3(256), 0, stream>>>(reg, xe, pval, pidx, out, lossArr);
  k_loss<<<dim3(1), dim3(256), 0, stream>>>(lossArr, out);
}

// Round 8
// 399.222 us; speedup vs baseline: 1.5176x; 1.0758x over previous
//
#include <hip/hip_runtime.h>
#include <hip/hip_bf16.h>

typedef unsigned short ushortT;
typedef __attribute__((ext_vector_type(8))) short v8s;
typedef __attribute__((ext_vector_type(4))) float v4f;

// Problem sizes (fixed by reference)
#define B_N   8192
#define S_N   512
#define F_N   64
#define R_N   4096
#define D_N   256
#define T_N   16
#define SF_N  (S_N * F_N)

#define ROWS  16            // rows per fused block
#define NBLK  (B_N / ROWS)  // 512 blocks

__device__ __forceinline__ ushortT f2bf(float x) {
  __hip_bfloat16 b = __float2bfloat16(x);
  return *(ushortT*)&b;
}
__device__ __forceinline__ float bf2f(ushortT u) {
  __hip_bfloat16 b = *(__hip_bfloat16*)&u;
  return __bfloat162float(b);
}
__device__ __forceinline__ void splitHL8(const float* v, v8s& h8, v8s& l8) {
  union { short s[8]; v8s v; } H, L;
#pragma unroll
  for (int j = 0; j < 8; ++j) {
    const float x = v[j];
    const ushortT hb = f2bf(x);
    H.s[j] = (short)hb;
    L.s[j] = (short)f2bf(x - bf2f(hb));
  }
  h8 = H.v; l8 = L.v;
}

// ---- K0: reg -> frag-swizzled bf16 H/L + rsqh --------------------------------
// Layout: regHs[((g*8 + k0)*64 + lane)*8 + j] holds reg[g*16 + (lane&15)][k0*32 + (lane>>4)*8 + j]
// so a wave's B-frag load for 16 cols x 32 ks is ONE contiguous 1 KB instruction.
__global__ __launch_bounds__(256) void k_prep(const float* __restrict__ reg,
                                              ushortT* __restrict__ regHs,
                                              ushortT* __restrict__ regLs,
                                              float* __restrict__ rsqh) {
  const int g = blockIdx.x;   // 16-col group (reg rows g*16..g*16+15)
  const int t = threadIdx.x;
  const int lane = t & 63;
  const int q = t >> 6;       // 0..3
  const int n16 = lane & 15;
  const int kg = lane >> 4;
  const int row = g * 16 + n16;
#pragma unroll
  for (int h = 0; h < 2; ++h) {
    const int k0 = q + h * 4;
    float v[8];
    *(float4*)&v[0] = *(const float4*)&reg[(size_t)row * D_N + k0 * 32 + kg * 8];
    *(float4*)&v[4] = *(const float4*)&reg[(size_t)row * D_N + k0 * 32 + kg * 8 + 4];
    v8s h8, l8;
    splitHL8(v, h8, l8);
    const size_t o = ((size_t)(g * 8 + k0) * 64 + lane) * 8;
    *(v8s*)&regHs[o] = h8;
    *(v8s*)&regLs[o] = l8;
  }
  // rsqh: r16 = t>>4, seg = t&15 -> 16 floats each, shfl-reduce over seg
  const int r16 = t >> 4, seg = t & 15;
  const float* rp = &reg[(size_t)(g * 16 + r16) * D_N + seg * 16];
  float s = 0.f;
#pragma unroll
  for (int j = 0; j < 4; ++j) {
    const float4 v = *(const float4*)&rp[j * 4];
    s += v.x * v.x + v.y * v.y + v.z * v.z + v.w * v.w;
  }
#pragma unroll
  for (int m = 8; m >= 1; m >>= 1) s += __shfl_xor(s, m);
  if (seg == 0) rsqh[g * 16 + r16] = 0.5f * s;
}

// ---- Fused: mean(16 rows) -> proj -> 3-pass MFMA score vs all 4096 -> emit ----
__global__ __launch_bounds__(512, 2) void k_fused(const float* __restrict__ x,
                                                  const float* __restrict__ W,
                                                  const float* __restrict__ bias,
                                                  const float* __restrict__ reg,
                                                  const ushortT* __restrict__ regHs,
                                                  const ushortT* __restrict__ regLs,
                                                  const float* __restrict__ rsqh,
                                                  float* __restrict__ out,
                                                  float* __restrict__ lossPart) {
  __shared__ __align__(16) float xm[ROWS][68];     // mean scratch (padded)
  __shared__ __align__(16) float xe_l[ROWS][260];  // xe fp32 (padded)
  __shared__ float swv[8][ROWS];
  __shared__ int   swi[8][ROWS];
  __shared__ float srowloss[ROWS];
  __shared__ int   sbi[ROWS];

  const int t = threadIdx.x;
  const int w = t >> 6;       // wave 0..7
  const int lane = t & 63;
  const int bm0 = blockIdx.x * ROWS;

  // ---------- Phase 1a: temporal mean; wave w -> rows 2w, 2w+1 ----------
  {
    const int r2 = lane >> 5;             // 0..1
    const int row = 2 * w + r2;
    const int sub = lane & 31;
    const int f4 = (sub & 15) * 4;
    const int sg2 = sub >> 4;             // 0..1 (s parity)
    const float* xb = x + (size_t)(bm0 + row) * SF_N + f4;
    float4 a0 = make_float4(0.f, 0.f, 0.f, 0.f);
    float4 a1 = make_float4(0.f, 0.f, 0.f, 0.f);
    for (int i = 0; i < S_N; i += 16) {   // 8 loads in flight per iter
      const float* p = xb + (size_t)(i + sg2) * F_N;
      const float4 v0 = *(const float4*)&p[0 * 2 * F_N];
      const float4 v1 = *(const float4*)&p[1 * 2 * F_N];
      const float4 v2 = *(const float4*)&p[2 * 2 * F_N];
      const float4 v3 = *(const float4*)&p[3 * 2 * F_N];
      const float4 v4 = *(const float4*)&p[4 * 2 * F_N];
      const float4 v5 = *(const float4*)&p[5 * 2 * F_N];
      const float4 v6 = *(const float4*)&p[6 * 2 * F_N];
      const float4 v7 = *(const float4*)&p[7 * 2 * F_N];
      a0.x += v0.x + v2.x; a0.y += v0.y + v2.y; a0.z += v0.z + v2.z; a0.w += v0.w + v2.w;
      a1.x += v1.x + v3.x; a1.y += v1.y + v3.y; a1.z += v1.z + v3.z; a1.w += v1.w + v3.w;
      a0.x += v4.x + v6.x; a0.y += v4.y + v6.y; a0.z += v4.z + v6.z; a0.w += v4.w + v6.w;
      a1.x += v5.x + v7.x; a1.y += v5.y + v7.y; a1.z += v5.z + v7.z; a1.w += v5.w + v7.w;
    }
    float sx = a0.x + a1.x, sy = a0.y + a1.y, sz = a0.z + a1.z, sw = a0.w + a1.w;
    sx += __shfl_xor(sx, 16); sy += __shfl_xor(sy, 16);
    sz += __shfl_xor(sz, 16); sw += __shfl_xor(sw, 16);
    if (sg2 == 0) {
      const float inv = 1.0f / (float)S_N;
      float4 o; o.x = sx * inv; o.y = sy * inv; o.z = sz * inv; o.w = sw * inv;
      *(float4*)&xm[row][f4] = o;
    }
  }
  __syncthreads();

  // ---------- Phase 1b: projection -> xe_l[16][256] ----------
  {
    const int prow = t >> 5;    // 0..15
    const int dg = t & 31;      // 8 d's each
#pragma unroll
    for (int dd = 0; dd < 8; ++dd) {
      const int d = dg * 8 + dd;
      float p = bias[d];
#pragma unroll
      for (int k4 = 0; k4 < 16; ++k4) {
        const float4 wv = *(const float4*)&W[(size_t)d * F_N + k4 * 4];
        const float4 xv = *(const float4*)&xm[prow][k4 * 4];
        p = fmaf(wv.x, xv.x, p); p = fmaf(wv.y, xv.y, p);
        p = fmaf(wv.z, xv.z, p); p = fmaf(wv.w, xv.w, p);
      }
      xe_l[prow][d] = p;
    }
  }
  __syncthreads();

  // ---------- Phase 2: A-frags from LDS (one-time), stream swizzled B, MFMA ----------
  const int n16 = lane & 15;
  const int kg = (lane >> 4) & 3;
  v8s ah[8], al[8];
#pragma unroll
  for (int k0 = 0; k0 < 8; ++k0) {
    float v[8];
    *(float4*)&v[0] = *(const float4*)&xe_l[n16][k0 * 32 + kg * 8];
    *(float4*)&v[4] = *(const float4*)&xe_l[n16][k0 * 32 + kg * 8 + 4];
    splitHL8(v, ah[k0], al[k0]);
  }

  float bvj[4];
  int bij[4];
#pragma unroll
  for (int j = 0; j < 4; ++j) { bvj[j] = 3.4e38f; bij[j] = 0; }

  for (int c = 0; c < 8; ++c) {
    const int g0 = w * 32 + c * 4;  // 16-col group base; cols (g0+ni)*16 + n16
    v4f acc[4];
#pragma unroll
    for (int ni = 0; ni < 4; ++ni) acc[ni] = (v4f){0.f, 0.f, 0.f, 0.f};
    const ushortT* BH = regHs + (size_t)g0 * 8 * 512 + lane * 8;
    const ushortT* BL = regLs + (size_t)g0 * 8 * 512 + lane * 8;
#pragma unroll
    for (int k0 = 0; k0 < 8; ++k0) {
      v8s bh[4], bl[4];
#pragma unroll
      for (int ni = 0; ni < 4; ++ni) {
        bh[ni] = *(const v8s*)&BH[(size_t)(ni * 8 + k0) * 512];
        bl[ni] = *(const v8s*)&BL[(size_t)(ni * 8 + k0) * 512];
      }
#pragma unroll
      for (int ni = 0; ni < 4; ++ni) {
        acc[ni] = __builtin_amdgcn_mfma_f32_16x16x32_bf16(ah[k0], bh[ni], acc[ni], 0, 0, 0);
        acc[ni] = __builtin_amdgcn_mfma_f32_16x16x32_bf16(ah[k0], bl[ni], acc[ni], 0, 0, 0);
        acc[ni] = __builtin_amdgcn_mfma_f32_16x16x32_bf16(al[k0], bh[ni], acc[ni], 0, 0, 0);
      }
    }
#pragma unroll
    for (int ni = 0; ni < 4; ++ni) {   // ascending col groups -> lowest idx on ties
      const float rq = rsqh[(g0 + ni) * 16 + n16];
      const int col = (g0 + ni) * 16 + n16;
#pragma unroll
      for (int j = 0; j < 4; ++j) {    // row = kg*4 + j
        const float s = rq - acc[ni][j];
        if (s < bvj[j]) { bvj[j] = s; bij[j] = col; }
      }
    }
  }

  // reduce over the 16 n16-lanes (cols); rows (kg,j) stay per-lane
#pragma unroll
  for (int j = 0; j < 4; ++j) {
    float v = bvj[j];
    int ix = bij[j];
#pragma unroll
    for (int m = 8; m >= 1; m >>= 1) {
      const float ov = __shfl_xor(v, m);
      const int oi = __shfl_xor(ix, m);
      if (ov < v || (ov == v && oi < ix)) { v = ov; ix = oi; }
    }
    if (n16 == 0) { swv[w][kg * 4 + j] = v; swi[w][kg * 4 + j] = ix; }
  }
  __syncthreads();

  // block-final argmin per row (waves = ascending col strips)
  if (t < ROWS) {
    float bv = swv[0][t];
    int bi = swi[0][t];
#pragma unroll
    for (int ww = 1; ww < 8; ++ww) {
      const float ov = swv[ww][t];
      const int oi = swi[ww][t];
      if (ov < bv || (ov == bv && oi < bi)) { bv = ov; bi = oi; }
    }
    sbi[t] = bi;
  }
  __syncthreads();

  // ---------- Phase 3: gather + emit 16 tokens/row + loss ----------
  {
    const int prow = t >> 5;   // 0..15
    const int dg = t & 31;     // 8 dims each
    const int d8 = dg * 8;
    const int gr = bm0 + prow;
    const int ix = sbi[prow];
    const float4 s0 = *(const float4*)&reg[(size_t)ix * D_N + d8];
    const float4 s1 = *(const float4*)&reg[(size_t)ix * D_N + d8 + 4];
#pragma unroll
    for (int tt = 0; tt < T_N; ++tt) {
      float* op = &out[((size_t)gr * T_N + tt) * D_N + d8];
      *(float4*)&op[0] = s0;
      *(float4*)&op[4] = s1;
    }
    const float4 x0 = *(const float4*)&xe_l[prow][d8];
    const float4 x1 = *(const float4*)&xe_l[prow][d8 + 4];
    float p = (x0.x - s0.x) * (x0.x - s0.x) + (x0.y - s0.y) * (x0.y - s0.y) +
              (x0.z - s0.z) * (x0.z - s0.z) + (x0.w - s0.w) * (x0.w - s0.w) +
              (x1.x - s1.x) * (x1.x - s1.x) + (x1.y - s1.y) * (x1.y - s1.y) +
              (x1.z - s1.z) * (x1.z - s1.z) + (x1.w - s1.w) * (x1.w - s1.w);
#pragma unroll
    for (int m = 16; m >= 1; m >>= 1) p += __shfl_xor(p, m);  // sum over 32 dg-lanes
    if (dg == 0) srowloss[prow] = p;
  }
  __syncthreads();
  if (t == 0) {
    float lp = 0.f;
#pragma unroll
    for (int r = 0; r < ROWS; ++r) lp += srowloss[r];
    lossPart[blockIdx.x] = lp;
  }
}

// ---- K2: loss = sum(parts)/B ----
__global__ __launch_bounds__(512) void k_loss(const float* __restrict__ lossPart,
                                              float* __restrict__ out) {
  __shared__ float ws8[8];
  const int t = threadIdx.x;
  float s = lossPart[t];  // exactly 512 parts
#pragma unroll
  for (int m = 32; m >= 1; m >>= 1) s += __shfl_xor(s, m);
  if ((t & 63) == 0) ws8[t >> 6] = s;
  __syncthreads();
  if (t == 0) {
    float a = 0.f;
#pragma unroll
    for (int i = 0; i < 8; ++i) a += ws8[i];
    out[(size_t)B_N * T_N * D_N] = a / (float)B_N;
  }
}

extern "C" void kernel_launch(void* const* d_in, const int* in_sizes, int n_in,
                              void* d_out, int out_size, void* d_ws, size_t ws_size,
                              hipStream_t stream) {
  const float* x    = (const float*)d_in[0];
  const float* W    = (const float*)d_in[1];
  const float* bias = (const float*)d_in[2];
  const float* reg  = (const float*)d_in[3];
  float* out = (float*)d_out;

  // workspace: all regions fully rewritten every call (~4 MB)
  ushortT* regHs = (ushortT*)d_ws;                      // 4096*256 bf16 (2 MB), swizzled
  ushortT* regLs = regHs + (size_t)R_N * D_N;           // 2 MB
  float*   rsqh  = (float*)(regLs + (size_t)R_N * D_N); // 4096
  float*   lossPart = rsqh + R_N;                       // 512

  k_prep<<<dim3(R_N / 16), dim3(256), 0, stream>>>(reg, regHs, regLs, rsqh);
  k_fused<<<dim3(NBLK), dim3(512), 0, stream>>>(x, W, bias, reg, regHs, regLs, rsqh,
                                                out, lossPart);
  k_loss<<<dim3(1), dim3(512), 0, stream>>>(lossPart, out);
}